// Round 2
// baseline (511.448 us; speedup 1.0000x reference)
//
#include <hip/hip_runtime.h>
#include <math.h>

// LearnableTD reverse scan: lambda_returns + sum_rewards.
//
// Affine recurrences (right-to-left), shared multiplier bt = gamma*(1-d)*lam:
//   sr_t = r_t                         + bt * sr_{t+1}      (init 0)
//   lr_t = r_t + gamma*(1-d)*(1-lam)*v + bt * lr_{t+1}      (init values[b][S])
//
// Kernel 1: precompute lam[t] (S floats) and gamma into d_ws — removes all
//           expf from the hot kernel (was 4/thread in 32768 blocks).
// Kernel 2: one block per row, 256 threads x 4 timesteps.
//   thread compose (4 steps) -> wave suffix scan via __shfl_down (6 steps,
//   no barriers) -> 4 wave aggregates through 12 floats of LDS with ONE
//   __syncthreads (was 16) -> replay producing both outputs.

#define DF_C 0.99f
#define AL_C 0.95f

__global__ void td_precompute_kernel(const float* __restrict__ raw_gamma,
                                     const float* __restrict__ raw_lambd,
                                     float* __restrict__ ws, int S) {
    const int t = blockIdx.x * blockDim.x + threadIdx.x;
    if (t < S) {
        const float s = 1.0f / (1.0f + expf(-raw_lambd[t]));
        ws[t] = AL_C + (1.0f - AL_C) * (2.0f * s - 1.0f);
    }
    if (t == 0) {
        const float s = 1.0f / (1.0f + expf(-raw_gamma[0]));
        ws[S] = DF_C + (1.0f - DF_C) * (2.0f * s - 1.0f);
    }
}

__global__ __launch_bounds__(256) void td_scan_kernel(
    const float* __restrict__ values,   // (B, S+1)
    const float* __restrict__ rewards,  // (B, S)
    const float* __restrict__ dones,    // (B, S)
    const float* __restrict__ lam_g,    // ws: lam[0..S-1], gamma at [S]
    float* __restrict__ out,            // [lambda_returns (B,S) | sum_rewards (B,S)]
    int B, int S)
{
    const int b    = blockIdx.x;
    const int tid  = threadIdx.x;
    const int lane = tid & 63;
    const int w    = tid >> 6;          // wave index 0..3
    const int t0   = tid * 4;

    const float gamma = lam_g[S];       // block-uniform -> scalar load

    // Coalesced float4 payload loads (t0*4B is 16B-aligned, rows are 4KB).
    const size_t rbase = (size_t)b * S + t0;
    const float4 r4 = *reinterpret_cast<const float4*>(rewards + rbase);
    const float4 d4 = *reinterpret_cast<const float4*>(dones   + rbase);
    const float4 l4 = *reinterpret_cast<const float4*>(lam_g   + t0);  // L2-hot
    const float* vrow = values + (size_t)b * (S + 1);

    float r[4]  = {r4.x, r4.y, r4.z, r4.w};
    float dd[4] = {d4.x, d4.y, d4.z, d4.w};
    float lm[4] = {l4.x, l4.y, l4.z, l4.w};
    float bt[4], c[4];

    // Local composition over this thread's 4 steps.
    // Affine triple (Al, As, Bp): carry_before = A + B * carry_after.
    float Al = 0.0f, As = 0.0f, Bp = 1.0f;
#pragma unroll
    for (int j = 0; j < 4; ++j) {
        const float vv = vrow[t0 + j + 1];          // v_next (dword, line-dense)
        const float g  = gamma * (1.0f - dd[j]);
        bt[j] = g * lm[j];
        c[j]  = g * (1.0f - lm[j]) * vv;
        Al += Bp * (r[j] + c[j]);
        As += Bp * r[j];
        Bp *= bt[j];
    }

    // Wave-level inclusive SUFFIX scan (compose with later lanes), 6 shfl steps.
    float al = Al, as_ = As, bb = Bp;
#pragma unroll
    for (int off = 1; off < 64; off <<= 1) {
        float pal = __shfl_down(al,  off, 64);
        float pas = __shfl_down(as_, off, 64);
        float pbb = __shfl_down(bb,  off, 64);
        const bool valid = (lane + off) < 64;
        pal = valid ? pal : 0.0f;
        pas = valid ? pas : 0.0f;
        pbb = valid ? pbb : 1.0f;
        al  = al  + bb * pal;     // self ∘ later
        as_ = as_ + bb * pas;
        bb  = bb  * pbb;
    }

    // Wave aggregate = lane 0's inclusive suffix (compose of all 64 lanes).
    __shared__ float wAl[4], wAs[4], wB[4];
    if (lane == 0) { wAl[w] = al; wAs[w] = as_; wB[w] = bb; }

    // Exclusive within-wave suffix = inclusive suffix of lane+1 (identity @63).
    float eal = __shfl_down(al,  1, 64);
    float eas = __shfl_down(as_, 1, 64);
    float ebb = __shfl_down(bb,  1, 64);
    if (lane == 63) { eal = 0.0f; eas = 0.0f; ebb = 1.0f; }

    __syncthreads();   // the ONLY barrier

    // E = Agg_{w+1} ∘ Agg_{w+2} ∘ Agg_3 (carry from later waves), wave-uniform.
    float EAl = 0.0f, EAs = 0.0f, EB = 1.0f;
    for (int u = w + 1; u < 4; ++u) {
        EAl = EAl + EB * wAl[u];
        EAs = EAs + EB * wAs[u];
        EB  = EB * wB[u];
    }

    // Apply to init: lr_init = values[b][S] (uniform), sr_init = 0.
    const float v_last = vrow[S];
    const float lr0 = EAl + EB * v_last;
    const float sr0 = EAs;

    // Thread's incoming carry = within-wave exclusive applied to wave carry.
    float lr = eal + ebb * lr0;
    float sr = eas + ebb * sr0;

    // Replay right-to-left producing the 4 outputs.
    float olr[4], osr[4];
#pragma unroll
    for (int j = 3; j >= 0; --j) {
        sr = r[j] + bt[j] * sr;
        lr = r[j] + c[j] + bt[j] * lr;
        olr[j] = lr;
        osr[j] = sr;
    }
    *reinterpret_cast<float4*>(out + rbase) =
        make_float4(olr[0], olr[1], olr[2], olr[3]);
    *reinterpret_cast<float4*>(out + (size_t)B * S + rbase) =
        make_float4(osr[0], osr[1], osr[2], osr[3]);
}

extern "C" void kernel_launch(void* const* d_in, const int* in_sizes, int n_in,
                              void* d_out, int out_size, void* d_ws, size_t ws_size,
                              hipStream_t stream) {
    const float* values    = (const float*)d_in[0];
    const float* rewards   = (const float*)d_in[1];
    const float* dones     = (const float*)d_in[2];
    const float* raw_gamma = (const float*)d_in[3];
    const float* raw_lambd = (const float*)d_in[4];
    float* out = (float*)d_out;
    float* ws  = (float*)d_ws;   // lam[S] + gamma, 4*(S+1) bytes

    const int S = in_sizes[4];       // raw_lambd has length S
    const int B = in_sizes[1] / S;   // rewards is B*S

    td_precompute_kernel<<<(S + 255) / 256, 256, 0, stream>>>(raw_gamma, raw_lambd, ws, S);
    td_scan_kernel<<<B, S / 4, 0, stream>>>(values, rewards, dones, ws, out, B, S);
}